// Round 11
// baseline (1336.491 us; speedup 1.0000x reference)
//
#include <hip/hip_runtime.h>

#define N_NODES 100000
#define EMB 64
#define N_EDGES 1280000
#define SCAN_TILE 1024   // nodes per scan block (256 threads x 4)
#define NPART 8          // node partitions == XCDs
#define PART_NODES 12500 // N_NODES / NPART
#define FILL_EPB 1024    // edges per fill block-chunk (256 threads x 4)
#define NCHUNKS (N_EDGES / FILL_EPB)  // 1250

typedef unsigned long long u64;
typedef _Float16 f16;
typedef __attribute__((ext_vector_type(2))) _Float16 f16x2;

// ---- degree count over destinations, 4 edges/thread; NT edge reads ----
__global__ void deg_kernel(const int* __restrict__ dst, int* __restrict__ deg) {
    int t = blockIdx.x * blockDim.x + threadIdx.x;
    int e = t * 4;
    if (e + 3 < N_EDGES) {
        u64 lo = __builtin_nontemporal_load((const u64*)(dst + e));
        u64 hi = __builtin_nontemporal_load((const u64*)(dst + e) + 1);
        atomicAdd(&deg[(unsigned)(lo & 0xffffffffu)], 1);
        atomicAdd(&deg[(unsigned)(lo >> 32)], 1);
        atomicAdd(&deg[(unsigned)(hi & 0xffffffffu)], 1);
        atomicAdd(&deg[(unsigned)(hi >> 32)], 1);
    }
}

// ---- dinv = deg^-0.5, rdinv = deg^0.5 (both 0 where deg==0) ----
__global__ void norm_kernel(const int* __restrict__ deg, float* __restrict__ dinv,
                            float* __restrict__ rdinv) {
    int i = blockIdx.x * blockDim.x + threadIdx.x;
    if (i < N_NODES) {
        int d = deg[i];
        float fd = (float)d;
        dinv[i]  = (d > 0) ? rsqrtf(fd) : 0.0f;
        rdinv[i] = (d > 0) ? sqrtf(fd) : 0.0f;
    }
}

// ---- y0 = dinv * emb, fp16, 4 elems/thread (all 4 in same node row) ----
__global__ void y0_kernel(const float* __restrict__ emb, const float* __restrict__ dinv,
                          f16* __restrict__ y0) {
    int i = blockIdx.x * blockDim.x + threadIdx.x;
    const int n4 = N_NODES * EMB / 4;
    if (i < n4) {
        float dv = dinv[i >> 4];  // 16 float4s per 64-dim row
        float4 v = ((const float4*)emb)[i];
        f16 h[4] = {(f16)(v.x * dv), (f16)(v.y * dv), (f16)(v.z * dv), (f16)(v.w * dv)};
        ((u64*)y0)[i] = *(const u64*)h;
    }
}

// ---- scan pass 1: per-block local exclusive scan + block sums ----
__global__ void scan1_kernel(const int* __restrict__ deg, int* __restrict__ local_scan,
                             int* __restrict__ block_sums) {
    __shared__ int lds[256];
    int base = blockIdx.x * SCAN_TILE;
    int vals[4];
    int tsum = 0;
#pragma unroll
    for (int k = 0; k < 4; ++k) {
        int i = base + threadIdx.x * 4 + k;
        vals[k] = (i < N_NODES) ? deg[i] : 0;
        tsum += vals[k];
    }
    lds[threadIdx.x] = tsum;
    __syncthreads();
    for (int off = 1; off < 256; off <<= 1) {
        int v = (threadIdx.x >= (unsigned)off) ? lds[threadIdx.x - off] : 0;
        __syncthreads();
        lds[threadIdx.x] += v;
        __syncthreads();
    }
    int texcl = lds[threadIdx.x] - tsum;
    if (threadIdx.x == 255) block_sums[blockIdx.x] = lds[255];
    int run = texcl;
#pragma unroll
    for (int k = 0; k < 4; ++k) {
        int i = base + threadIdx.x * 4 + k;
        if (i < N_NODES) local_scan[i] = run;
        run += vals[k];
    }
}

// ---- scan pass 2: exclusive scan of the 98 block sums (single block) ----
__global__ void scan2_kernel(int* __restrict__ block_sums, int nb) {
    __shared__ int lds[128];
    int v = (threadIdx.x < (unsigned)nb) ? block_sums[threadIdx.x] : 0;
    lds[threadIdx.x] = v;
    __syncthreads();
    for (int off = 1; off < 128; off <<= 1) {
        int t = (threadIdx.x >= (unsigned)off) ? lds[threadIdx.x - off] : 0;
        __syncthreads();
        lds[threadIdx.x] += t;
        __syncthreads();
    }
    if (threadIdx.x < (unsigned)nb) block_sums[threadIdx.x] = lds[threadIdx.x] - v;
}

// ---- scan pass 3: add block offsets; init cursor; cap row_start ----
__global__ void scan3_kernel(int* __restrict__ row_start, const int* __restrict__ block_sums,
                             int* __restrict__ cursor) {
    int i = blockIdx.x * blockDim.x + threadIdx.x;
    if (i < N_NODES) {
        int v = row_start[i] + block_sums[i / SCAN_TILE];
        row_start[i] = v;
        cursor[i] = v;
    }
    if (i == 0) row_start[N_NODES] = N_EDGES;
}

// ---- XCD-affine CSR fill with per-partition chunk queues ----
// Block reads its REAL XCD id (HW_REG_XCC_ID, wave-uniform) and drains its own
// partition's chunk queue first -> partition p's cursor+col slice (~690 KB)
// stays in ONE XCD's L2 and scatter writes merge before writeback. Fallback
// scan over other queues guarantees every (chunk, partition) pair is processed
// exactly once regardless of the dispatch->XCD mapping.
__global__ void fill_part_kernel(const int* __restrict__ src, const int* __restrict__ dst,
                                 int* __restrict__ cursor, int* __restrict__ col,
                                 int* __restrict__ qcnt) {
    int xcc;
    asm volatile("s_getreg_b32 %0, hwreg(HW_REG_XCC_ID)" : "=s"(xcc));
    int p0 = xcc & (NPART - 1);
    __shared__ int s_chunk;
    for (int pp = 0; pp < NPART; ++pp) {
        int part = (p0 + pp) & (NPART - 1);
        int lo = part * PART_NODES;
        int hi = lo + PART_NODES;
        for (;;) {
            if (threadIdx.x == 0) s_chunk = atomicAdd(&qcnt[part], 1);
            __syncthreads();
            int chunk = s_chunk;
            __syncthreads();
            if (chunk >= NCHUNKS) break;   // uniform
            int e = chunk * FILL_EPB + threadIdx.x * 4;
            u64 dlo = __builtin_nontemporal_load((const u64*)(dst + e));
            u64 dhi = __builtin_nontemporal_load((const u64*)(dst + e) + 1);
            int d0 = (int)(dlo & 0xffffffffu), d1 = (int)(dlo >> 32);
            int d2 = (int)(dhi & 0xffffffffu), d3 = (int)(dhi >> 32);
            if (d0 >= lo && d0 < hi)
                col[atomicAdd(&cursor[d0], 1)] = __builtin_nontemporal_load(&src[e]);
            if (d1 >= lo && d1 < hi)
                col[atomicAdd(&cursor[d1], 1)] = __builtin_nontemporal_load(&src[e + 1]);
            if (d2 >= lo && d2 < hi)
                col[atomicAdd(&cursor[d2], 1)] = __builtin_nontemporal_load(&src[e + 2]);
            if (d3 >= lo && d3 < hi)
                col[atomicAdd(&cursor[d3], 1)] = __builtin_nontemporal_load(&src[e + 3]);
        }
    }
}

// ---- propagation: one wave per destination row, two slots, 8-deep MLP ----
// Lane = (slot s, dim-pair j). All __shfl ops exec-uniform (R9 lesson).
// Hierarchical unroll 8/4/tail: the 8-body holds 8 independent 128 B gathers
// in flight (loads hoisted before accumulates) to lift the latency-bound
// ~2.5 TB/s miss-service plateau (VGPR 12 -> deliberately higher).
template <bool FINAL>
__global__ void gather_kernel(const int* __restrict__ row_start, const int* __restrict__ col,
                              const float* __restrict__ dinv, const float* __restrict__ rdinv,
                              const f16* __restrict__ yin, f16* __restrict__ yout,
                              const float* __restrict__ emb,
                              const f16* __restrict__ y1, const f16* __restrict__ y2,
                              float* __restrict__ out) {
    unsigned int gid = blockIdx.x * blockDim.x + threadIdx.x;
    unsigned int row = gid >> 6;       // wave-uniform
    int lane = (int)(gid & 63u);
    int s = lane >> 5;   // edge slot 0/1
    int j = lane & 31;   // dim pair: dims 2j, 2j+1
    if (row >= N_NODES) return;        // wave-uniform exit
    int beg = row_start[row];
    int end = row_start[row + 1];
    const f16* yj = yin + 2 * j;       // lane-fixed dim offset
    float accx = 0.0f, accy = 0.0f;
    for (int cb = beg; cb < end; cb += 64) {   // uniform bounds
        int idx = cb + lane;
        int ci = 0;
        if (idx < end) ci = __builtin_nontemporal_load(&col[idx]);
        int n = end - cb;
        if (n > 64) n = 64;            // uniform
        int kk = 0;
        for (; kk + 8 <= n; kk += 8) { // 4 edges per slot: 8 gathers in flight/wave
            int c0 = __shfl(ci, kk + s);
            int c1 = __shfl(ci, kk + s + 2);
            int c2 = __shfl(ci, kk + s + 4);
            int c3 = __shfl(ci, kk + s + 6);
            unsigned u0 = *(const unsigned*)(yj + (unsigned)c0 * EMB);
            unsigned u1 = *(const unsigned*)(yj + (unsigned)c1 * EMB);
            unsigned u2 = *(const unsigned*)(yj + (unsigned)c2 * EMB);
            unsigned u3 = *(const unsigned*)(yj + (unsigned)c3 * EMB);
            f16x2 h0 = __builtin_bit_cast(f16x2, u0);
            f16x2 h1 = __builtin_bit_cast(f16x2, u1);
            f16x2 h2 = __builtin_bit_cast(f16x2, u2);
            f16x2 h3 = __builtin_bit_cast(f16x2, u3);
            accx += (float)h0.x + (float)h1.x + (float)h2.x + (float)h3.x;
            accy += (float)h0.y + (float)h1.y + (float)h2.y + (float)h3.y;
        }
        if (kk + 4 <= n) {             // uniform
            int c0 = __shfl(ci, kk + s);
            int c1 = __shfl(ci, kk + s + 2);
            unsigned u0 = *(const unsigned*)(yj + (unsigned)c0 * EMB);
            unsigned u1 = *(const unsigned*)(yj + (unsigned)c1 * EMB);
            f16x2 h0 = __builtin_bit_cast(f16x2, u0);
            f16x2 h1 = __builtin_bit_cast(f16x2, u1);
            accx += (float)h0.x + (float)h1.x;
            accy += (float)h0.y + (float)h1.y;
            kk += 4;
        }
        for (; kk < n; ++kk) {         // <=3 edges; shfl converged, acc predicated
            int c = __shfl(ci, kk);
            if (s == (kk & 1)) {
                unsigned u = *(const unsigned*)(yj + (unsigned)c * EMB);
                f16x2 h = __builtin_bit_cast(f16x2, u);
                accx += (float)h.x;
                accy += (float)h.y;
            }
        }
    }
    // merge the two edge slots (converged)
    accx += __shfl_xor(accx, 32);
    accy += __shfl_xor(accy, 32);
    if (s == 0) {
        float dv = dinv[row];
        unsigned int o = row * EMB + 2 * (unsigned)j;
        if (!FINAL) {
            float sc = dv * dv;
            f16x2 h;
            h.x = (f16)(accx * sc);
            h.y = (f16)(accy * sc);
            __builtin_nontemporal_store(__builtin_bit_cast(unsigned, h), (unsigned*)(yout + o));
        } else {
            float rv = rdinv[row];
            float2 e2 = *(const float2*)(emb + o);
            f16x2 a = __builtin_bit_cast(f16x2, *(const unsigned*)(y1 + o));
            f16x2 b = __builtin_bit_cast(f16x2, *(const unsigned*)(y2 + o));
            float rx = 0.25f * (e2.x + rv * ((float)a.x + (float)b.x) + dv * accx);
            float ry = 0.25f * (e2.y + rv * ((float)a.y + (float)b.y) + dv * accy);
            __builtin_nontemporal_store(rx, out + o);
            __builtin_nontemporal_store(ry, out + o + 1);
        }
    }
}

extern "C" void kernel_launch(void* const* d_in, const int* in_sizes, int n_in,
                              void* d_out, int out_size, void* d_ws, size_t ws_size,
                              hipStream_t stream) {
    const int*   edge = (const int*)d_in[0];   // (2, N_EDGES) row-major
    const int*   src  = edge;
    const int*   dst  = edge + N_EDGES;
    const float* emb  = (const float*)d_in[1]; // (N_NODES, 64) fp32
    float*       out  = (float*)d_out;

    // workspace carve (16B-aligned offsets), ~45 MB total
    char* ws = (char*)d_ws;
    size_t off = 0;
    int* deg       = (int*)(ws + off); off += 400000;  // reused as cursor
    int* row_start = (int*)(ws + off); off += 400016;
    int* bsums     = (int*)(ws + off); off += 512;
    int* qcnt      = (int*)(ws + off); off += 64;      // 8 chunk-queue counters
    float* dinv    = (float*)(ws + off); off += 400000;
    float* rdinv   = (float*)(ws + off); off += 400000;
    int* col       = (int*)(ws + off); off += (size_t)N_EDGES * 4;         // 5.12 MB
    f16* y0        = (f16*)(ws + off); off += (size_t)N_NODES * EMB * 2;   // 12.8 MB
    f16* y1        = (f16*)(ws + off); off += (size_t)N_NODES * EMB * 2;   // 12.8 MB
    f16* y2        = (f16*)(ws + off); off += (size_t)N_NODES * EMB * 2;   // 12.8 MB

    const int NB = (N_NODES + SCAN_TILE - 1) / SCAN_TILE;  // 98

    // ---- CSR build (once per call; reused by all 3 layers) ----
    hipMemsetAsync(deg, 0, (size_t)N_NODES * sizeof(int), stream);
    hipMemsetAsync(qcnt, 0, 8 * sizeof(int), stream);
    deg_kernel<<<(N_EDGES / 4 + 255) / 256, 256, 0, stream>>>(dst, deg);
    norm_kernel<<<(N_NODES + 255) / 256, 256, 0, stream>>>(deg, dinv, rdinv);
    y0_kernel<<<(N_NODES * EMB / 4 + 255) / 256, 256, 0, stream>>>(emb, dinv, y0);
    scan1_kernel<<<NB, 256, 0, stream>>>(deg, row_start, bsums);
    scan2_kernel<<<1, 128, 0, stream>>>(bsums, NB);
    scan3_kernel<<<(N_NODES + 255) / 256, 256, 0, stream>>>(row_start, bsums, deg /*cursor*/);
    fill_part_kernel<<<NCHUNKS * NPART, 256, 0, stream>>>(src, dst, deg /*cursor*/, col, qcnt);

    // ---- 3 propagation layers (pure y-sums), final fuses the 1/4-sum ----
    const unsigned int gthreads = (unsigned int)N_NODES * EMB;
    const int gblocks = (int)((gthreads + 255) / 256);
    gather_kernel<false><<<gblocks, 256, 0, stream>>>(row_start, col, dinv, rdinv,
                                                      y0, y1, emb, y1, y2, out);
    gather_kernel<false><<<gblocks, 256, 0, stream>>>(row_start, col, dinv, rdinv,
                                                      y1, y2, emb, y1, y2, out);
    gather_kernel<true><<<gblocks, 256, 0, stream>>>(row_start, col, dinv, rdinv,
                                                     y2, (f16*)0, emb, y1, y2, out);
}

// Round 12
// 339.746 us; speedup vs baseline: 3.9338x; 3.9338x over previous
//
#include <hip/hip_runtime.h>

#define N_NODES 100000
#define EMB 64
#define N_EDGES 1280000
#define SCAN_TILE 1024   // nodes per scan block (256 threads x 4)
#define NPART 8          // node partitions (concurrency heuristic)
#define PART_NODES 12500 // N_NODES / NPART
#define FILL_EPB 1024    // edges per fill block (256 threads x 4)

typedef unsigned long long u64;
typedef _Float16 f16;
typedef __attribute__((ext_vector_type(2))) _Float16 f16x2;

// ---- degree count over destinations, 4 edges/thread (cached: dst re-used by fill) ----
__global__ void deg_kernel(const int* __restrict__ dst, int* __restrict__ deg) {
    int t = blockIdx.x * blockDim.x + threadIdx.x;
    int e = t * 4;
    if (e + 3 < N_EDGES) {
        int4 d4 = *(const int4*)(dst + e);
        atomicAdd(&deg[d4.x], 1);
        atomicAdd(&deg[d4.y], 1);
        atomicAdd(&deg[d4.z], 1);
        atomicAdd(&deg[d4.w], 1);
    }
}

// ---- dinv = deg^-0.5, rdinv = deg^0.5 (both 0 where deg==0) ----
__global__ void norm_kernel(const int* __restrict__ deg, float* __restrict__ dinv,
                            float* __restrict__ rdinv) {
    int i = blockIdx.x * blockDim.x + threadIdx.x;
    if (i < N_NODES) {
        int d = deg[i];
        float fd = (float)d;
        dinv[i]  = (d > 0) ? rsqrtf(fd) : 0.0f;
        rdinv[i] = (d > 0) ? sqrtf(fd) : 0.0f;
    }
}

// ---- y0 = dinv * emb, fp16, cached store (y0 is gathered next -> keep in L2/L3) ----
__global__ void y0_kernel(const float* __restrict__ emb, const float* __restrict__ dinv,
                          f16* __restrict__ y0) {
    int i = blockIdx.x * blockDim.x + threadIdx.x;
    const int n4 = N_NODES * EMB / 4;
    if (i < n4) {
        float dv = dinv[i >> 4];  // 16 float4s per 64-dim row
        float4 v = ((const float4*)emb)[i];
        f16 h[4] = {(f16)(v.x * dv), (f16)(v.y * dv), (f16)(v.z * dv), (f16)(v.w * dv)};
        ((u64*)y0)[i] = *(const u64*)h;
    }
}

// ---- scan pass 1: per-block local exclusive scan + block sums ----
__global__ void scan1_kernel(const int* __restrict__ deg, int* __restrict__ local_scan,
                             int* __restrict__ block_sums) {
    __shared__ int lds[256];
    int base = blockIdx.x * SCAN_TILE;
    int vals[4];
    int tsum = 0;
#pragma unroll
    for (int k = 0; k < 4; ++k) {
        int i = base + threadIdx.x * 4 + k;
        vals[k] = (i < N_NODES) ? deg[i] : 0;
        tsum += vals[k];
    }
    lds[threadIdx.x] = tsum;
    __syncthreads();
    for (int off = 1; off < 256; off <<= 1) {
        int v = (threadIdx.x >= (unsigned)off) ? lds[threadIdx.x - off] : 0;
        __syncthreads();
        lds[threadIdx.x] += v;
        __syncthreads();
    }
    int texcl = lds[threadIdx.x] - tsum;
    if (threadIdx.x == 255) block_sums[blockIdx.x] = lds[255];
    int run = texcl;
#pragma unroll
    for (int k = 0; k < 4; ++k) {
        int i = base + threadIdx.x * 4 + k;
        if (i < N_NODES) local_scan[i] = run;
        run += vals[k];
    }
}

// ---- scan pass 2: exclusive scan of the 98 block sums (single block) ----
__global__ void scan2_kernel(int* __restrict__ block_sums, int nb) {
    __shared__ int lds[128];
    int v = (threadIdx.x < (unsigned)nb) ? block_sums[threadIdx.x] : 0;
    lds[threadIdx.x] = v;
    __syncthreads();
    for (int off = 1; off < 128; off <<= 1) {
        int t = (threadIdx.x >= (unsigned)off) ? lds[threadIdx.x - off] : 0;
        __syncthreads();
        lds[threadIdx.x] += t;
        __syncthreads();
    }
    if (threadIdx.x < (unsigned)nb) block_sums[threadIdx.x] = lds[threadIdx.x] - v;
}

// ---- scan pass 3: add block offsets; init cursor; cap row_start ----
__global__ void scan3_kernel(int* __restrict__ row_start, const int* __restrict__ block_sums,
                             int* __restrict__ cursor) {
    int i = blockIdx.x * blockDim.x + threadIdx.x;
    if (i < N_NODES) {
        int v = row_start[i] + block_sums[i / SCAN_TILE];
        row_start[i] = v;
        cursor[i] = v;
    }
    if (i == 0) row_start[N_NODES] = N_EDGES;
}

// ---- partitioned CSR fill (static R10 scheme; all loads cached so dst/src
// stay L3-resident across the 8 passes) ----
__global__ void fill_part_kernel(const int* __restrict__ src, const int* __restrict__ dst,
                                 int* __restrict__ cursor, int* __restrict__ col) {
    int part = blockIdx.x & (NPART - 1);
    int chunk = blockIdx.x >> 3;
    int e = chunk * FILL_EPB + threadIdx.x * 4;
    int lo = part * PART_NODES;
    int hi = lo + PART_NODES;
    if (e + 3 < N_EDGES) {
        int4 d4 = *(const int4*)(dst + e);
        if (d4.x >= lo && d4.x < hi) col[atomicAdd(&cursor[d4.x], 1)] = src[e];
        if (d4.y >= lo && d4.y < hi) col[atomicAdd(&cursor[d4.y], 1)] = src[e + 1];
        if (d4.z >= lo && d4.z < hi) col[atomicAdd(&cursor[d4.z], 1)] = src[e + 2];
        if (d4.w >= lo && d4.w < hi) col[atomicAdd(&cursor[d4.w], 1)] = src[e + 3];
    }
}

// ---- propagation: one wave per destination row, two slots, 8-deep MLP ----
// Lane = (slot s, dim-pair j). All __shfl ops exec-uniform (R9 lesson).
// ALL loads/stores cached (except final out): y layers live in L2/L3 so the
// random 128 B row gathers are L3 hits, not ~900-cycle HBM misses.
template <bool FINAL>
__global__ void gather_kernel(const int* __restrict__ row_start, const int* __restrict__ col,
                              const float* __restrict__ dinv, const float* __restrict__ rdinv,
                              const f16* __restrict__ yin, f16* __restrict__ yout,
                              const float* __restrict__ emb,
                              const f16* __restrict__ y1, const f16* __restrict__ y2,
                              float* __restrict__ out) {
    unsigned int gid = blockIdx.x * blockDim.x + threadIdx.x;
    unsigned int row = gid >> 6;       // wave-uniform
    int lane = (int)(gid & 63u);
    int s = lane >> 5;   // edge slot 0/1
    int j = lane & 31;   // dim pair: dims 2j, 2j+1
    if (row >= N_NODES) return;        // wave-uniform exit
    int beg = row_start[row];
    int end = row_start[row + 1];
    const f16* yj = yin + 2 * j;       // lane-fixed dim offset
    float accx = 0.0f, accy = 0.0f;
    for (int cb = beg; cb < end; cb += 64) {   // uniform bounds
        int idx = cb + lane;
        int ci = 0;
        if (idx < end) ci = col[idx];
        int n = end - cb;
        if (n > 64) n = 64;            // uniform
        int kk = 0;
        for (; kk + 8 <= n; kk += 8) { // 4 edges per slot: 8 gathers in flight/wave
            int c0 = __shfl(ci, kk + s);
            int c1 = __shfl(ci, kk + s + 2);
            int c2 = __shfl(ci, kk + s + 4);
            int c3 = __shfl(ci, kk + s + 6);
            unsigned u0 = *(const unsigned*)(yj + (unsigned)c0 * EMB);
            unsigned u1 = *(const unsigned*)(yj + (unsigned)c1 * EMB);
            unsigned u2 = *(const unsigned*)(yj + (unsigned)c2 * EMB);
            unsigned u3 = *(const unsigned*)(yj + (unsigned)c3 * EMB);
            f16x2 h0 = __builtin_bit_cast(f16x2, u0);
            f16x2 h1 = __builtin_bit_cast(f16x2, u1);
            f16x2 h2 = __builtin_bit_cast(f16x2, u2);
            f16x2 h3 = __builtin_bit_cast(f16x2, u3);
            accx += (float)h0.x + (float)h1.x + (float)h2.x + (float)h3.x;
            accy += (float)h0.y + (float)h1.y + (float)h2.y + (float)h3.y;
        }
        if (kk + 4 <= n) {             // uniform
            int c0 = __shfl(ci, kk + s);
            int c1 = __shfl(ci, kk + s + 2);
            unsigned u0 = *(const unsigned*)(yj + (unsigned)c0 * EMB);
            unsigned u1 = *(const unsigned*)(yj + (unsigned)c1 * EMB);
            f16x2 h0 = __builtin_bit_cast(f16x2, u0);
            f16x2 h1 = __builtin_bit_cast(f16x2, u1);
            accx += (float)h0.x + (float)h1.x;
            accy += (float)h0.y + (float)h1.y;
            kk += 4;
        }
        for (; kk < n; ++kk) {         // <=3 edges; shfl converged, acc predicated
            int c = __shfl(ci, kk);
            if (s == (kk & 1)) {
                unsigned u = *(const unsigned*)(yj + (unsigned)c * EMB);
                f16x2 h = __builtin_bit_cast(f16x2, u);
                accx += (float)h.x;
                accy += (float)h.y;
            }
        }
    }
    // merge the two edge slots (converged)
    accx += __shfl_xor(accx, 32);
    accy += __shfl_xor(accy, 32);
    if (s == 0) {
        float dv = dinv[row];
        unsigned int o = row * EMB + 2 * (unsigned)j;
        if (!FINAL) {
            float sc = dv * dv;
            f16x2 h;
            h.x = (f16)(accx * sc);
            h.y = (f16)(accy * sc);
            *(unsigned*)(yout + o) = __builtin_bit_cast(unsigned, h);  // cached: re-read next layer
        } else {
            float rv = rdinv[row];
            float2 e2 = *(const float2*)(emb + o);
            f16x2 a = __builtin_bit_cast(f16x2, *(const unsigned*)(y1 + o));
            f16x2 b = __builtin_bit_cast(f16x2, *(const unsigned*)(y2 + o));
            float rx = 0.25f * (e2.x + rv * ((float)a.x + (float)b.x) + dv * accx);
            float ry = 0.25f * (e2.y + rv * ((float)a.y + (float)b.y) + dv * accy);
            __builtin_nontemporal_store(rx, out + o);      // out is never re-read
            __builtin_nontemporal_store(ry, out + o + 1);
        }
    }
}

extern "C" void kernel_launch(void* const* d_in, const int* in_sizes, int n_in,
                              void* d_out, int out_size, void* d_ws, size_t ws_size,
                              hipStream_t stream) {
    const int*   edge = (const int*)d_in[0];   // (2, N_EDGES) row-major
    const int*   src  = edge;
    const int*   dst  = edge + N_EDGES;
    const float* emb  = (const float*)d_in[1]; // (N_NODES, 64) fp32
    float*       out  = (float*)d_out;

    // workspace carve (16B-aligned offsets), ~45 MB total
    char* ws = (char*)d_ws;
    size_t off = 0;
    int* deg       = (int*)(ws + off); off += 400000;  // reused as cursor
    int* row_start = (int*)(ws + off); off += 400016;
    int* bsums     = (int*)(ws + off); off += 512;
    float* dinv    = (float*)(ws + off); off += 400000;
    float* rdinv   = (float*)(ws + off); off += 400000;
    int* col       = (int*)(ws + off); off += (size_t)N_EDGES * 4;         // 5.12 MB
    f16* y0        = (f16*)(ws + off); off += (size_t)N_NODES * EMB * 2;   // 12.8 MB
    f16* y1        = (f16*)(ws + off); off += (size_t)N_NODES * EMB * 2;   // 12.8 MB
    f16* y2        = (f16*)(ws + off); off += (size_t)N_NODES * EMB * 2;   // 12.8 MB

    const int NB = (N_NODES + SCAN_TILE - 1) / SCAN_TILE;  // 98

    // ---- CSR build (once per call; reused by all 3 layers) ----
    hipMemsetAsync(deg, 0, (size_t)N_NODES * sizeof(int), stream);
    deg_kernel<<<(N_EDGES / 4 + 255) / 256, 256, 0, stream>>>(dst, deg);
    norm_kernel<<<(N_NODES + 255) / 256, 256, 0, stream>>>(deg, dinv, rdinv);
    y0_kernel<<<(N_NODES * EMB / 4 + 255) / 256, 256, 0, stream>>>(emb, dinv, y0);
    scan1_kernel<<<NB, 256, 0, stream>>>(deg, row_start, bsums);
    scan2_kernel<<<1, 128, 0, stream>>>(bsums, NB);
    scan3_kernel<<<(N_NODES + 255) / 256, 256, 0, stream>>>(row_start, bsums, deg /*cursor*/);
    fill_part_kernel<<<(N_EDGES / FILL_EPB) * NPART, 256, 0, stream>>>(src, dst,
                                                                      deg /*cursor*/, col);

    // ---- 3 propagation layers (pure y-sums), final fuses the 1/4-sum ----
    const unsigned int gthreads = (unsigned int)N_NODES * EMB;
    const int gblocks = (int)((gthreads + 255) / 256);
    gather_kernel<false><<<gblocks, 256, 0, stream>>>(row_start, col, dinv, rdinv,
                                                      y0, y1, emb, y1, y2, out);
    gather_kernel<false><<<gblocks, 256, 0, stream>>>(row_start, col, dinv, rdinv,
                                                      y1, y2, emb, y1, y2, out);
    gather_kernel<true><<<gblocks, 256, 0, stream>>>(row_start, col, dinv, rdinv,
                                                     y2, (f16*)0, emb, y1, y2, out);
}